// Round 1
// baseline (194.219 us; speedup 1.0000x reference)
//
#include <hip/hip_runtime.h>
#include <hip/hip_bf16.h>

// Embedding gather: out[token, :] = w[x[token], :]
// B=8, S=2048 -> 16384 tokens; DIM=1024 fp32; VOCAB=32000.
// One block per token; 256 threads x float4 = 1024 floats = one row.
__global__ __launch_bounds__(256) void embed_gather_kernel(
    const int* __restrict__ x, const float* __restrict__ w,
    float* __restrict__ out, int n_tokens) {
  int token = blockIdx.x;
  if (token >= n_tokens) return;
  int row = x[token];  // wave-uniform -> scalar load
  const float4* src = reinterpret_cast<const float4*>(w + (size_t)row * 1024);
  float4* dst = reinterpret_cast<float4*>(out + (size_t)token * 1024);
  dst[threadIdx.x] = src[threadIdx.x];
}

extern "C" void kernel_launch(void* const* d_in, const int* in_sizes, int n_in,
                              void* d_out, int out_size, void* d_ws, size_t ws_size,
                              hipStream_t stream) {
  const int* x = (const int*)d_in[0];     // [B*S] int32 token ids
  const float* w = (const float*)d_in[1]; // [VOCAB, DIM] fp32
  float* out = (float*)d_out;             // [B*S, DIM] fp32
  int n_tokens = in_sizes[0];             // 16384
  embed_gather_kernel<<<n_tokens, 256, 0, stream>>>(x, w, out, n_tokens);
}